// Round 1
// baseline (105.451 us; speedup 1.0000x reference)
//
#include <hip/hip_runtime.h>
#include <math.h>

constexpr int B = 32, S = 4096, I = 512, H = 512;
constexpr int CH = 128;          // s-positions per workgroup in main pass
constexpr int NCH = S / CH;      // 32 chunks per batch row
constexpr float NEGV = -1e18f;

// workspace layout (float offsets)
constexpr size_t WS_WKD   = 0;                    // [512]  Wk^T @ Wout
constexpr size_t WS_WQD   = 512;                  // [512]  Wq^T @ Wout
constexpr size_t WS_CC    = 1024;                 // [1]    (bq+bk)·Wout
constexpr size_t WS_OFF   = 1056;                 // [32]   per-batch score offset
constexpr size_t WS_WKT   = 2048;                 // [512*512] Wk transposed [i][h]
constexpr size_t WS_PARTS = WS_WKT + (size_t)I*H; // [B*NCH*514] m,l,ctx[512]

// ---------------------------------------------------------------------------
// prep: blocks 0..7 -> wkd tiles, 8..15 -> wqd tiles, 16 -> scalar cc,
//       17..80 -> transpose Wk into wkT
// ---------------------------------------------------------------------------
__global__ __launch_bounds__(256) void prep_kernel(
    const float* __restrict__ Wq, const float* __restrict__ bq,
    const float* __restrict__ Wk, const float* __restrict__ bk,
    const float* __restrict__ Wout, float* __restrict__ ws) {
  __shared__ float sh[64 * 65];
  int blk = blockIdx.x;
  int t = threadIdx.x, wv = t >> 6, ln = t & 63;

  if (blk < 16) {
    // wkd[i] = sum_h W[h,i] * Wout[h]  (column dot), 64 columns per block
    bool isQ = blk >= 8;
    const float* W = isQ ? Wq : Wk;
    float* out = ws + (isQ ? WS_WQD : WS_WKD);
    int j = (blk & 7) * 64;
    float p = 0.f;
    int h0 = wv * 128;
    for (int h = h0; h < h0 + 128; ++h)
      p = fmaf(W[(size_t)h * I + j + ln], Wout[h], p);
    sh[wv * 64 + ln] = p;
    __syncthreads();
    if (t < 64) out[j + t] = sh[t] + sh[64 + t] + sh[128 + t] + sh[192 + t];
  } else if (blk == 16) {
    float p = 0.f;
    for (int h = t; h < H; h += 256) p = fmaf(bq[h] + bk[h], Wout[h], p);
    sh[t] = p;
    __syncthreads();
    for (int o = 128; o; o >>= 1) {
      if (t < o) sh[t] += sh[t + o];
      __syncthreads();
    }
    if (t == 0) ws[WS_CC] = sh[0];
  } else {
    // transpose 64x64 tile of Wk -> wkT[i*H + h]
    int tt = blk - 17;
    int tr = tt >> 3, tc = tt & 7;   // tr: h-tile, tc: i-tile
    float* wkT = ws + WS_WKT;
    for (int k = 0; k < 16; ++k) {
      int r = wv * 16 + k;           // local h
      sh[r * 65 + ln] = Wk[(size_t)(tr * 64 + r) * I + tc * 64 + ln];
    }
    __syncthreads();
    for (int k = 0; k < 16; ++k) {
      int r2 = wv * 16 + k;          // local i
      wkT[(size_t)(tc * 64 + r2) * H + tr * 64 + ln] = sh[ln * 65 + r2];
    }
  }
}

// ---------------------------------------------------------------------------
// prep2: off[b] = query[b,:]·wqd + cc     (one wave per batch)
// ---------------------------------------------------------------------------
__global__ __launch_bounds__(64) void prep2_kernel(
    const float* __restrict__ query, float* __restrict__ ws) {
  const float* wqd = ws + WS_WQD;
  int b = blockIdx.x, ln = threadIdx.x;
  float p = 0.f;
  for (int i = ln; i < I; i += 64) p = fmaf(query[(size_t)b * I + i], wqd[i], p);
  #pragma unroll
  for (int o = 32; o; o >>= 1) p += __shfl_xor(p, o, 64);
  if (ln == 0) ws[WS_OFF + b] = p + ws[WS_CC];
}

// ---------------------------------------------------------------------------
// main: one pass over key. Per (b, chunk) block: 4 waves, one s-row per wave
// per step. Online softmax with per-wave running (m, l, ctx[8]/lane).
// Writes attn_weight directly and one (m,l,ctx[512]) partial per block.
// ---------------------------------------------------------------------------
__global__ __launch_bounds__(256, 4) void main_kernel(
    const float* __restrict__ key, const int* __restrict__ mask,
    float* __restrict__ ws, float* __restrict__ attn_w) {
  const float* wkd = ws + WS_WKD;
  const float* offv = ws + WS_OFF;
  float* parts = ws + WS_PARTS;

  int b = blockIdx.x, cidx = blockIdx.y;
  int t = threadIdx.x, wv = t >> 6, ln = t & 63;

  const float* kb = key + ((size_t)b * S + (size_t)cidx * CH) * I;
  const int* mrow = mask + (size_t)b * S + cidx * CH;
  float* awrow = attn_w + (size_t)b * S + cidx * CH;

  // lane's slice of wkd: i = 4*ln + j  and  i = 256 + 4*ln + j
  float4 wA = *(const float4*)(wkd + ln * 4);
  float4 wB = *(const float4*)(wkd + 256 + ln * 4);
  float offb = offv[b];

  float m = -INFINITY, l = 0.f;
  float4 cA = {0.f, 0.f, 0.f, 0.f}, cB = {0.f, 0.f, 0.f, 0.f};

  const float* kr0 = kb + (size_t)wv * I;
  float4 a = *(const float4*)(kr0 + ln * 4);
  float4 bb = *(const float4*)(kr0 + 256 + ln * 4);

  #pragma unroll 2
  for (int s = wv; s < CH; s += 4) {
    float4 ac = a, bc = bb;
    int sn = (s + 4 < CH) ? s + 4 : s;          // clamped prefetch
    const float* kn = kb + (size_t)sn * I;
    a = *(const float4*)(kn + ln * 4);
    bb = *(const float4*)(kn + 256 + ln * 4);

    float d = ac.x * wA.x;
    d = fmaf(ac.y, wA.y, d); d = fmaf(ac.z, wA.z, d); d = fmaf(ac.w, wA.w, d);
    d = fmaf(bc.x, wB.x, d); d = fmaf(bc.y, wB.y, d);
    d = fmaf(bc.z, wB.z, d); d = fmaf(bc.w, wB.w, d);
    #pragma unroll
    for (int o = 32; o; o >>= 1) d += __shfl_xor(d, o, 64);

    float score = offb + d;
    float seff = (mrow[s] != 0) ? NEGV : score;
    if (ln == 0) awrow[s] = seff;

    float mnew = fmaxf(m, seff);
    float scale = __expf(m - mnew);             // exp(-inf)=0 handles init
    float e = __expf(seff - mnew);              // underflows to 0 when masked
    l = fmaf(l, scale, e);
    cA.x = fmaf(cA.x, scale, e * ac.x);
    cA.y = fmaf(cA.y, scale, e * ac.y);
    cA.z = fmaf(cA.z, scale, e * ac.z);
    cA.w = fmaf(cA.w, scale, e * ac.w);
    cB.x = fmaf(cB.x, scale, e * bc.x);
    cB.y = fmaf(cB.y, scale, e * bc.y);
    cB.z = fmaf(cB.z, scale, e * bc.z);
    cB.w = fmaf(cB.w, scale, e * bc.w);
    m = mnew;
  }

  // combine the 4 waves' online states into one block partial
  __shared__ float shm[4], shl[4];
  __shared__ float shc[4][512];
  if (ln == 0) { shm[wv] = m; shl[wv] = l; }
  *(float4*)&shc[wv][ln * 4] = cA;
  *(float4*)&shc[wv][256 + ln * 4] = cB;
  __syncthreads();

  float mb = fmaxf(fmaxf(shm[0], shm[1]), fmaxf(shm[2], shm[3]));
  float ew0 = __expf(shm[0] - mb), ew1 = __expf(shm[1] - mb);
  float ew2 = __expf(shm[2] - mb), ew3 = __expf(shm[3] - mb);
  float* slot = parts + ((size_t)b * NCH + cidx) * 514;
  if (t == 0) {
    slot[0] = mb;
    slot[1] = shl[0] * ew0 + shl[1] * ew1 + shl[2] * ew2 + shl[3] * ew3;
  }
  for (int i = t; i < I; i += 256) {
    float acc = shc[0][i] * ew0;
    acc = fmaf(shc[1][i], ew1, acc);
    acc = fmaf(shc[2][i], ew2, acc);
    acc = fmaf(shc[3][i], ew3, acc);
    slot[2 + i] = acc;
  }
}

// ---------------------------------------------------------------------------
// finish: combine 32 chunk-partials per batch -> ctx[512], then
// attn[b,h] = ctx·wkT[:,h] + bk[h].  grid (B, 4), 128 threads (h quadrant).
// ---------------------------------------------------------------------------
__global__ __launch_bounds__(128) void finish_kernel(
    const float* __restrict__ bk, float* __restrict__ ws,
    float* __restrict__ attn) {
  const float* parts = ws + WS_PARTS;
  const float* wkT = ws + WS_WKT;
  int b = blockIdx.x, hq = blockIdx.y, t = threadIdx.x;

  __shared__ float mlds[NCH], llds[NCH], elds[NCH], ctx[I];
  const float* pb = parts + (size_t)b * NCH * 514;
  if (t < NCH) {
    mlds[t] = pb[t * 514];
    llds[t] = pb[t * 514 + 1];
  }
  __syncthreads();
  float m = -INFINITY;
  #pragma unroll
  for (int p = 0; p < NCH; ++p) m = fmaxf(m, mlds[p]);
  if (t < NCH) elds[t] = __expf(mlds[t] - m);
  __syncthreads();
  float l = 0.f;
  #pragma unroll
  for (int p = 0; p < NCH; ++p) l = fmaf(llds[p], elds[p], l);
  float invl = 1.f / l;

  for (int i = t; i < I; i += 128) {
    float acc = 0.f;
    #pragma unroll 4
    for (int p = 0; p < NCH; ++p) acc = fmaf(pb[p * 514 + 2 + i], elds[p], acc);
    ctx[i] = acc * invl;
  }
  __syncthreads();

  int h = hq * 128 + t;
  float acc = bk[h];
  #pragma unroll 4
  for (int i = 0; i < I; ++i) acc = fmaf(ctx[i], wkT[(size_t)i * H + h], acc);
  attn[(size_t)b * H + h] = acc;
}

// ---------------------------------------------------------------------------
extern "C" void kernel_launch(void* const* d_in, const int* in_sizes, int n_in,
                              void* d_out, int out_size, void* d_ws, size_t ws_size,
                              hipStream_t stream) {
  const float* query = (const float*)d_in[0];   // [B, I]
  const float* key   = (const float*)d_in[1];   // [B, S, I]
  const int*   mask  = (const int*)d_in[2];     // [B, S]
  const float* Wq    = (const float*)d_in[3];   // [H, I]
  const float* bq    = (const float*)d_in[4];   // [H]
  const float* Wk    = (const float*)d_in[5];   // [H, I]
  const float* bk    = (const float*)d_in[6];   // [H]
  const float* Wout  = (const float*)d_in[7];   // [H]

  float* attn   = (float*)d_out;                // [B, H]
  float* attn_w = (float*)d_out + (size_t)B * H;// [B, S]
  float* ws     = (float*)d_ws;

  prep_kernel<<<81, 256, 0, stream>>>(Wq, bq, Wk, bk, Wout, ws);
  prep2_kernel<<<B, 64, 0, stream>>>(query, ws);
  main_kernel<<<dim3(B, NCH), 256, 0, stream>>>(key, mask, ws, attn_w);
  finish_kernel<<<dim3(B, 4), 128, 0, stream>>>(bk, ws, attn);
}

// Round 2
// 101.286 us; speedup vs baseline: 1.0411x; 1.0411x over previous
//
#include <hip/hip_runtime.h>
#include <math.h>

constexpr int B = 32, S = 4096, I = 512, H = 512;
constexpr int CH = 128;          // s-positions per workgroup in main pass
constexpr int NCH = S / CH;      // 32 chunks per batch row
constexpr float NEGV = -1e18f;

// workspace layout (float offsets)
constexpr size_t WS_WKD   = 0;                    // [512]  Wk^T @ Wout
constexpr size_t WS_WQD   = 512;                  // [512]  Wq^T @ Wout
constexpr size_t WS_CC    = 1024;                 // [1]    (bq+bk)·Wout
constexpr size_t WS_WKT   = 2048;                 // [512*512] Wk transposed [i][h]
constexpr size_t WS_PARTS = WS_WKT + (size_t)I*H; // [B*NCH*514] m,l,ctx[512]

// ---------------------------------------------------------------------------
// prep: blocks 0..7 -> wkd tiles, 8..15 -> wqd tiles, 16 -> scalar cc,
//       17..80 -> transpose Wk into wkT
// ---------------------------------------------------------------------------
__global__ __launch_bounds__(256) void prep_kernel(
    const float* __restrict__ Wq, const float* __restrict__ bq,
    const float* __restrict__ Wk, const float* __restrict__ bk,
    const float* __restrict__ Wout, float* __restrict__ ws) {
  __shared__ float sh[64 * 65];
  int blk = blockIdx.x;
  int t = threadIdx.x, wv = t >> 6, ln = t & 63;

  if (blk < 16) {
    // wkd[i] = sum_h W[h,i] * Wout[h]  (column dot), 64 columns per block
    bool isQ = blk >= 8;
    const float* W = isQ ? Wq : Wk;
    float* out = ws + (isQ ? WS_WQD : WS_WKD);
    int j = (blk & 7) * 64;
    float p = 0.f;
    int h0 = wv * 128;
    for (int h = h0; h < h0 + 128; ++h)
      p = fmaf(W[(size_t)h * I + j + ln], Wout[h], p);
    sh[wv * 64 + ln] = p;
    __syncthreads();
    if (t < 64) out[j + t] = sh[t] + sh[64 + t] + sh[128 + t] + sh[192 + t];
  } else if (blk == 16) {
    float p = 0.f;
    for (int h = t; h < H; h += 256) p = fmaf(bq[h] + bk[h], Wout[h], p);
    sh[t] = p;
    __syncthreads();
    for (int o = 128; o; o >>= 1) {
      if (t < o) sh[t] += sh[t + o];
      __syncthreads();
    }
    if (t == 0) ws[WS_CC] = sh[0];
  } else {
    // transpose 64x64 tile of Wk -> wkT[i*H + h]
    int tt = blk - 17;
    int tr = tt >> 3, tc = tt & 7;   // tr: h-tile, tc: i-tile
    float* wkT = ws + WS_WKT;
    for (int k = 0; k < 16; ++k) {
      int r = wv * 16 + k;           // local h
      sh[r * 65 + ln] = Wk[(size_t)(tr * 64 + r) * I + tc * 64 + ln];
    }
    __syncthreads();
    for (int k = 0; k < 16; ++k) {
      int r2 = wv * 16 + k;          // local i
      wkT[(size_t)(tc * 64 + r2) * H + tr * 64 + ln] = sh[ln * 65 + r2];
    }
  }
}

// ---------------------------------------------------------------------------
// main: one pass over key. Per (b, chunk) block: 4 waves; each wave processes
// TWO s-rows per iteration (independent reduce chains for ILP). Online
// softmax with increase-only rescale branch (wave-uniform, rare) so the
// common path has no loop-carried dependency through the reduce/exp chain.
// ---------------------------------------------------------------------------
__global__ __launch_bounds__(256) void main_kernel(
    const float* __restrict__ query,
    const float* __restrict__ key, const int* __restrict__ mask,
    float* __restrict__ ws, float* __restrict__ attn_w) {
  const float* wkd = ws + WS_WKD;
  const float* wqd = ws + WS_WQD;
  float* parts = ws + WS_PARTS;

  int b = blockIdx.x, cidx = blockIdx.y;
  int t = threadIdx.x, wv = t >> 6, ln = t & 63;

  // per-wave redundant off[b] = query[b,:]·wqd + cc   (L2-hot, ~25 instrs)
  float offb;
  {
    const float* qb = query + (size_t)b * I;
    float p = qb[ln] * wqd[ln];
    #pragma unroll
    for (int k = 1; k < 8; ++k)
      p = fmaf(qb[ln + 64 * k], wqd[ln + 64 * k], p);
    #pragma unroll
    for (int o = 32; o; o >>= 1) p += __shfl_xor(p, o, 64);
    offb = p + ws[WS_CC];
  }

  const float* kb = key + ((size_t)b * S + (size_t)cidx * CH) * I;
  const int* mrow = mask + (size_t)b * S + cidx * CH;
  float* awrow = attn_w + (size_t)b * S + cidx * CH;

  // lane's slice of wkd: i = 4*ln + j  and  i = 256 + 4*ln + j
  float4 wA = *(const float4*)(wkd + ln * 4);
  float4 wB = *(const float4*)(wkd + 256 + ln * 4);

  float m = -INFINITY, l = 0.f;
  float4 cA = {0.f, 0.f, 0.f, 0.f}, cB = {0.f, 0.f, 0.f, 0.f};

  // wave wv owns row pairs {2wv, 2wv+1} stepping by 8
  const float* kr0 = kb + (size_t)(wv * 2) * I + ln * 4;
  float4 a0 = *(const float4*)(kr0);
  float4 b0 = *(const float4*)(kr0 + 256);
  float4 a1 = *(const float4*)(kr0 + 512);
  float4 b1 = *(const float4*)(kr0 + 768);

  for (int s = wv * 2; s < CH; s += 8) {
    float4 ca0 = a0, cb0 = b0, ca1 = a1, cb1 = b1;
    int sn = (s + 8 < CH) ? s + 8 : s;          // clamped prefetch
    const float* kn = kb + (size_t)sn * I + ln * 4;
    a0 = *(const float4*)(kn);
    b0 = *(const float4*)(kn + 256);
    a1 = *(const float4*)(kn + 512);
    b1 = *(const float4*)(kn + 768);

    float d0 = ca0.x * wA.x, d1 = ca1.x * wA.x;
    d0 = fmaf(ca0.y, wA.y, d0); d1 = fmaf(ca1.y, wA.y, d1);
    d0 = fmaf(ca0.z, wA.z, d0); d1 = fmaf(ca1.z, wA.z, d1);
    d0 = fmaf(ca0.w, wA.w, d0); d1 = fmaf(ca1.w, wA.w, d1);
    d0 = fmaf(cb0.x, wB.x, d0); d1 = fmaf(cb1.x, wB.x, d1);
    d0 = fmaf(cb0.y, wB.y, d0); d1 = fmaf(cb1.y, wB.y, d1);
    d0 = fmaf(cb0.z, wB.z, d0); d1 = fmaf(cb1.z, wB.z, d1);
    d0 = fmaf(cb0.w, wB.w, d0); d1 = fmaf(cb1.w, wB.w, d1);
    #pragma unroll
    for (int o = 32; o; o >>= 1) {
      d0 += __shfl_xor(d0, o, 64);
      d1 += __shfl_xor(d1, o, 64);
    }

    int2 mm = *(const int2*)(mrow + s);
    float s0 = mm.x ? NEGV : (offb + d0);
    float s1 = mm.y ? NEGV : (offb + d1);
    if (ln == 0) *(float2*)(awrow + s) = float2{s0, s1};

    float mx = fmaxf(s0, s1);
    if (mx > m) {                               // wave-uniform, rare (~H(32))
      float sc = __expf(m - mx);                // exp(-inf)=0 handles init
      l *= sc;
      cA.x *= sc; cA.y *= sc; cA.z *= sc; cA.w *= sc;
      cB.x *= sc; cB.y *= sc; cB.z *= sc; cB.w *= sc;
      m = mx;
    }
    float e0 = __expf(s0 - m);                  // <= 1 by construction
    float e1 = __expf(s1 - m);
    l += e0 + e1;
    cA.x = fmaf(e0, ca0.x, fmaf(e1, ca1.x, cA.x));
    cA.y = fmaf(e0, ca0.y, fmaf(e1, ca1.y, cA.y));
    cA.z = fmaf(e0, ca0.z, fmaf(e1, ca1.z, cA.z));
    cA.w = fmaf(e0, ca0.w, fmaf(e1, ca1.w, cA.w));
    cB.x = fmaf(e0, cb0.x, fmaf(e1, cb1.x, cB.x));
    cB.y = fmaf(e0, cb0.y, fmaf(e1, cb1.y, cB.y));
    cB.z = fmaf(e0, cb0.z, fmaf(e1, cb1.z, cB.z));
    cB.w = fmaf(e0, cb0.w, fmaf(e1, cb1.w, cB.w));
  }

  // combine the 4 waves' online states into one block partial
  __shared__ float shm[4], shl[4];
  __shared__ float shc[4][512];
  if (ln == 0) { shm[wv] = m; shl[wv] = l; }
  *(float4*)&shc[wv][ln * 4] = cA;
  *(float4*)&shc[wv][256 + ln * 4] = cB;
  __syncthreads();

  float mb = fmaxf(fmaxf(shm[0], shm[1]), fmaxf(shm[2], shm[3]));
  float ew0 = __expf(shm[0] - mb), ew1 = __expf(shm[1] - mb);
  float ew2 = __expf(shm[2] - mb), ew3 = __expf(shm[3] - mb);
  float* slot = parts + ((size_t)b * NCH + cidx) * 514;
  if (t == 0) {
    slot[0] = mb;
    slot[1] = shl[0] * ew0 + shl[1] * ew1 + shl[2] * ew2 + shl[3] * ew3;
  }
  for (int i = t; i < I; i += 256) {
    float acc = shc[0][i] * ew0;
    acc = fmaf(shc[1][i], ew1, acc);
    acc = fmaf(shc[2][i], ew2, acc);
    acc = fmaf(shc[3][i], ew3, acc);
    slot[2 + i] = acc;
  }
}

// ---------------------------------------------------------------------------
// finish: combine 32 chunk-partials per batch -> ctx[512], then
// attn[b,h] = ctx·wkT[:,h] + bk[h].  grid (B, 4), 128 threads (h quadrant).
// ---------------------------------------------------------------------------
__global__ __launch_bounds__(128) void finish_kernel(
    const float* __restrict__ bk, float* __restrict__ ws,
    float* __restrict__ attn) {
  const float* parts = ws + WS_PARTS;
  const float* wkT = ws + WS_WKT;
  int b = blockIdx.x, hq = blockIdx.y, t = threadIdx.x;

  __shared__ float mlds[NCH], llds[NCH], elds[NCH], ctx[I];
  const float* pb = parts + (size_t)b * NCH * 514;
  if (t < NCH) {
    mlds[t] = pb[t * 514];
    llds[t] = pb[t * 514 + 1];
  }
  __syncthreads();
  float m = -INFINITY;
  #pragma unroll
  for (int p = 0; p < NCH; ++p) m = fmaxf(m, mlds[p]);
  if (t < NCH) elds[t] = __expf(mlds[t] - m);
  __syncthreads();
  float l = 0.f;
  #pragma unroll
  for (int p = 0; p < NCH; ++p) l = fmaf(llds[p], elds[p], l);
  float invl = 1.f / l;

  for (int i = t; i < I; i += 128) {
    float acc = 0.f;
    #pragma unroll 4
    for (int p = 0; p < NCH; ++p) acc = fmaf(pb[p * 514 + 2 + i], elds[p], acc);
    ctx[i] = acc * invl;
  }
  __syncthreads();

  int h = hq * 128 + t;
  float acc = bk[h];
  #pragma unroll 4
  for (int i = 0; i < I; ++i) acc = fmaf(ctx[i], wkT[(size_t)i * H + h], acc);
  attn[(size_t)b * H + h] = acc;
}

// ---------------------------------------------------------------------------
extern "C" void kernel_launch(void* const* d_in, const int* in_sizes, int n_in,
                              void* d_out, int out_size, void* d_ws, size_t ws_size,
                              hipStream_t stream) {
  const float* query = (const float*)d_in[0];   // [B, I]
  const float* key   = (const float*)d_in[1];   // [B, S, I]
  const int*   mask  = (const int*)d_in[2];     // [B, S]
  const float* Wq    = (const float*)d_in[3];   // [H, I]
  const float* bq    = (const float*)d_in[4];   // [H]
  const float* Wk    = (const float*)d_in[5];   // [H, I]
  const float* bk    = (const float*)d_in[6];   // [H]
  const float* Wout  = (const float*)d_in[7];   // [H]

  float* attn   = (float*)d_out;                // [B, H]
  float* attn_w = (float*)d_out + (size_t)B * H;// [B, S]
  float* ws     = (float*)d_ws;

  prep_kernel<<<81, 256, 0, stream>>>(Wq, bq, Wk, bk, Wout, ws);
  main_kernel<<<dim3(B, NCH), 256, 0, stream>>>(query, key, mask, ws, attn_w);
  finish_kernel<<<dim3(B, 4), 128, 0, stream>>>(bk, ws, attn);
}

// Round 3
// 67.518 us; speedup vs baseline: 1.5618x; 1.5001x over previous
//
#include <hip/hip_runtime.h>
#include <math.h>

constexpr int B = 32, S = 4096, I = 512, H = 512;
constexpr int CH = 128;          // s-positions per workgroup in main pass
constexpr int NCH = S / CH;      // 32 chunks per batch row
constexpr float NEGV = -1e18f;

// workspace layout (float offsets)
constexpr size_t WS_WKD   = 0;                    // [512]  Wk^T @ Wout
constexpr size_t WS_WQD   = 512;                  // [512]  Wq^T @ Wout
constexpr size_t WS_CC    = 1024;                 // [1]    (bq+bk)·Wout
constexpr size_t WS_WKT   = 2048;                 // [512*512] Wk transposed [i][h]
constexpr size_t WS_PARTS = WS_WKT + (size_t)I*H; // [B*NCH*514] m,l,ctx[512]

// ---------------------------------------------------------------------------
// prep: blocks 0..7 -> wkd tiles, 8..15 -> wqd tiles, 16 -> scalar cc,
//       17..80 -> transpose Wk into wkT
// ---------------------------------------------------------------------------
__global__ __launch_bounds__(256) void prep_kernel(
    const float* __restrict__ Wq, const float* __restrict__ bq,
    const float* __restrict__ Wk, const float* __restrict__ bk,
    const float* __restrict__ Wout, float* __restrict__ ws) {
  __shared__ float sh[64 * 65];
  int blk = blockIdx.x;
  int t = threadIdx.x, wv = t >> 6, ln = t & 63;

  if (blk < 16) {
    bool isQ = blk >= 8;
    const float* W = isQ ? Wq : Wk;
    float* out = ws + (isQ ? WS_WQD : WS_WKD);
    int j = (blk & 7) * 64;
    float p = 0.f;
    int h0 = wv * 128;
    for (int h = h0; h < h0 + 128; ++h)
      p = fmaf(W[(size_t)h * I + j + ln], Wout[h], p);
    sh[wv * 64 + ln] = p;
    __syncthreads();
    if (t < 64) out[j + t] = sh[t] + sh[64 + t] + sh[128 + t] + sh[192 + t];
  } else if (blk == 16) {
    float p = 0.f;
    for (int h = t; h < H; h += 256) p = fmaf(bq[h] + bk[h], Wout[h], p);
    sh[t] = p;
    __syncthreads();
    for (int o = 128; o; o >>= 1) {
      if (t < o) sh[t] += sh[t + o];
      __syncthreads();
    }
    if (t == 0) ws[WS_CC] = sh[0];
  } else {
    int tt = blk - 17;
    int tr = tt >> 3, tc = tt & 7;   // tr: h-tile, tc: i-tile
    float* wkT = ws + WS_WKT;
    for (int k = 0; k < 16; ++k) {
      int r = wv * 16 + k;           // local h
      sh[r * 65 + ln] = Wk[(size_t)(tr * 64 + r) * I + tc * 64 + ln];
    }
    __syncthreads();
    for (int k = 0; k < 16; ++k) {
      int r2 = wv * 16 + k;          // local i
      wkT[(size_t)(tc * 64 + r2) * H + tr * 64 + ln] = sh[ln * 65 + r2];
    }
  }
}

// ---------------------------------------------------------------------------
// main: one pass over key. 4 waves/block, 2 rows/wave/iter, 16 iters.
// DEPTH-2 register pipeline: loads for iter t+2 issued while computing t,
// so 8 dwordx4 loads (8 KB) stay in flight per wave (vmcnt(8) steady state).
// ---------------------------------------------------------------------------
__global__ __launch_bounds__(256, 4) void main_kernel(
    const float* __restrict__ query,
    const float* __restrict__ key, const int* __restrict__ mask,
    float* __restrict__ ws, float* __restrict__ attn_w) {
  const float* wkd = ws + WS_WKD;
  const float* wqd = ws + WS_WQD;
  float* parts = ws + WS_PARTS;

  int b = blockIdx.x, cidx = blockIdx.y;
  int t = threadIdx.x, wv = t >> 6, ln = t & 63;

  // per-wave redundant off[b] = query[b,:]·wqd + cc   (L2-hot)
  float offb;
  {
    const float* qb = query + (size_t)b * I;
    float p = qb[ln] * wqd[ln];
    #pragma unroll
    for (int k = 1; k < 8; ++k)
      p = fmaf(qb[ln + 64 * k], wqd[ln + 64 * k], p);
    #pragma unroll
    for (int o = 32; o; o >>= 1) p += __shfl_xor(p, o, 64);
    offb = p + ws[WS_CC];
  }

  const float* kb = key + ((size_t)b * S + (size_t)cidx * CH) * I;
  const int* mrow = mask + (size_t)b * S + cidx * CH;
  float* awrow = attn_w + (size_t)b * S + cidx * CH;

  float4 wA = *(const float4*)(wkd + ln * 4);
  float4 wB = *(const float4*)(wkd + 256 + ln * 4);

  float m = -INFINITY, l = 0.f;
  float4 cA = {0.f, 0.f, 0.f, 0.f}, cB = {0.f, 0.f, 0.f, 0.f};

  // iter it: rows s = wv*2 + it*8, s+1.  16 iterations.
  const float* lanep = kb + (size_t)(wv * 2) * I + ln * 4;
  constexpr int ROWSTEP = 8 * I;     // floats per iteration step

  // prologue: iters 0 (u) and 1 (v)
  float4 uA0 = *(const float4*)(lanep);
  float4 uB0 = *(const float4*)(lanep + 256);
  float4 uA1 = *(const float4*)(lanep + 512);
  float4 uB1 = *(const float4*)(lanep + 768);
  float4 vA0 = *(const float4*)(lanep + ROWSTEP);
  float4 vB0 = *(const float4*)(lanep + ROWSTEP + 256);
  float4 vA1 = *(const float4*)(lanep + ROWSTEP + 512);
  float4 vB1 = *(const float4*)(lanep + ROWSTEP + 768);

  #pragma unroll 2
  for (int it = 0; it < 16; ++it) {
    int s = wv * 2 + it * 8;
    // issue iter it+2 (clamped to a valid, L2-hot address on the tail)
    int itn = (it + 2 < 16) ? it + 2 : it;
    const float* kn = lanep + (size_t)itn * ROWSTEP;
    float4 nA0 = *(const float4*)(kn);
    float4 nB0 = *(const float4*)(kn + 256);
    float4 nA1 = *(const float4*)(kn + 512);
    float4 nB1 = *(const float4*)(kn + 768);

    float d0 = uA0.x * wA.x, d1 = uA1.x * wA.x;
    d0 = fmaf(uA0.y, wA.y, d0); d1 = fmaf(uA1.y, wA.y, d1);
    d0 = fmaf(uA0.z, wA.z, d0); d1 = fmaf(uA1.z, wA.z, d1);
    d0 = fmaf(uA0.w, wA.w, d0); d1 = fmaf(uA1.w, wA.w, d1);
    d0 = fmaf(uB0.x, wB.x, d0); d1 = fmaf(uB1.x, wB.x, d1);
    d0 = fmaf(uB0.y, wB.y, d0); d1 = fmaf(uB1.y, wB.y, d1);
    d0 = fmaf(uB0.z, wB.z, d0); d1 = fmaf(uB1.z, wB.z, d1);
    d0 = fmaf(uB0.w, wB.w, d0); d1 = fmaf(uB1.w, wB.w, d1);
    #pragma unroll
    for (int o = 32; o; o >>= 1) {
      d0 += __shfl_xor(d0, o, 64);
      d1 += __shfl_xor(d1, o, 64);
    }

    int2 mm = *(const int2*)(mrow + s);
    float s0 = mm.x ? NEGV : (offb + d0);
    float s1 = mm.y ? NEGV : (offb + d1);
    if (ln == 0) *(float2*)(awrow + s) = float2{s0, s1};

    float mx = fmaxf(s0, s1);
    if (mx > m) {                               // wave-uniform, rare
      float sc = __expf(m - mx);                // exp(-inf)=0 handles init
      l *= sc;
      cA.x *= sc; cA.y *= sc; cA.z *= sc; cA.w *= sc;
      cB.x *= sc; cB.y *= sc; cB.z *= sc; cB.w *= sc;
      m = mx;
    }
    float e0 = __expf(s0 - m);
    float e1 = __expf(s1 - m);
    l += e0 + e1;
    cA.x = fmaf(e0, uA0.x, fmaf(e1, uA1.x, cA.x));
    cA.y = fmaf(e0, uA0.y, fmaf(e1, uA1.y, cA.y));
    cA.z = fmaf(e0, uA0.z, fmaf(e1, uA1.z, cA.z));
    cA.w = fmaf(e0, uA0.w, fmaf(e1, uA1.w, cA.w));
    cB.x = fmaf(e0, uB0.x, fmaf(e1, uB1.x, cB.x));
    cB.y = fmaf(e0, uB0.y, fmaf(e1, uB1.y, cB.y));
    cB.z = fmaf(e0, uB0.z, fmaf(e1, uB1.z, cB.z));
    cB.w = fmaf(e0, uB0.w, fmaf(e1, uB1.w, cB.w));

    // rotate pipeline registers (renamed away by the unroll)
    uA0 = vA0; uB0 = vB0; uA1 = vA1; uB1 = vB1;
    vA0 = nA0; vB0 = nB0; vA1 = nA1; vB1 = nB1;
  }

  // combine the 4 waves' online states into one block partial
  __shared__ float shm[4], shl[4];
  __shared__ float shc[4][512];
  if (ln == 0) { shm[wv] = m; shl[wv] = l; }
  *(float4*)&shc[wv][ln * 4] = cA;
  *(float4*)&shc[wv][256 + ln * 4] = cB;
  __syncthreads();

  float mb = fmaxf(fmaxf(shm[0], shm[1]), fmaxf(shm[2], shm[3]));
  float ew0 = __expf(shm[0] - mb), ew1 = __expf(shm[1] - mb);
  float ew2 = __expf(shm[2] - mb), ew3 = __expf(shm[3] - mb);
  float* slot = parts + ((size_t)b * NCH + cidx) * 514;
  if (t == 0) {
    slot[0] = mb;
    slot[1] = shl[0] * ew0 + shl[1] * ew1 + shl[2] * ew2 + shl[3] * ew3;
  }
  for (int i = t; i < I; i += 256) {
    float acc = shc[0][i] * ew0;
    acc = fmaf(shc[1][i], ew1, acc);
    acc = fmaf(shc[2][i], ew2, acc);
    acc = fmaf(shc[3][i], ew3, acc);
    slot[2 + i] = acc;
  }
}

// ---------------------------------------------------------------------------
// finish: grid (B, 4), 256 threads. All loops restructured for MLP:
// ctx-combine has 32 independent loads/thread; GEMV splits i across
// thread-halves (128 h × 2 halves) with unroll-16, then LDS pair-reduce.
// ---------------------------------------------------------------------------
__global__ __launch_bounds__(256) void finish_kernel(
    const float* __restrict__ bk, float* __restrict__ ws,
    float* __restrict__ attn) {
  const float* parts = ws + WS_PARTS;
  const float* wkT = ws + WS_WKT;
  int b = blockIdx.x, hq = blockIdx.y, t = threadIdx.x;

  __shared__ float eld[NCH], ctx[I], red[256];
  const float* pb = parts + (size_t)b * NCH * 514;

  // every thread computes m, l (broadcast loads, L2-hot)
  float m = -INFINITY;
  #pragma unroll
  for (int p = 0; p < NCH; ++p) m = fmaxf(m, pb[p * 514]);
  float l = 0.f;
  #pragma unroll
  for (int p = 0; p < NCH; ++p) l = fmaf(pb[p * 514 + 1], __expf(pb[p * 514] - m), l);
  float invl = 1.f / l;
  if (t < NCH) eld[t] = __expf(pb[t * 514] - m) * invl;   // invl folded in
  __syncthreads();

  // ctx: thread owns i = t and i = t+256; 32 independent loads each
  {
    float a0 = 0.f, a1 = 0.f;
    #pragma unroll 8
    for (int p = 0; p < NCH; ++p) {
      float e = eld[p];
      a0 = fmaf(pb[p * 514 + 2 + t], e, a0);
      a1 = fmaf(pb[p * 514 + 258 + t], e, a1);
    }
    ctx[t] = a0;
    ctx[t + 256] = a1;
  }
  __syncthreads();

  // GEMV: h = hq*128 + (t&127); thread-half ih covers 256 i-values
  int h = hq * 128 + (t & 127);
  int ih = t >> 7;
  const float* wc = wkT + (size_t)(ih * 256) * H + h;
  const float* cc = ctx + ih * 256;
  float acc = 0.f;
  #pragma unroll 16
  for (int i = 0; i < 256; ++i) acc = fmaf(cc[i], wc[(size_t)i * H], acc);
  red[t] = acc;
  __syncthreads();
  if (t < 128) attn[(size_t)b * H + h] = red[t] + red[t + 128] + bk[h];
}

// ---------------------------------------------------------------------------
extern "C" void kernel_launch(void* const* d_in, const int* in_sizes, int n_in,
                              void* d_out, int out_size, void* d_ws, size_t ws_size,
                              hipStream_t stream) {
  const float* query = (const float*)d_in[0];   // [B, I]
  const float* key   = (const float*)d_in[1];   // [B, S, I]
  const int*   mask  = (const int*)d_in[2];     // [B, S]
  const float* Wq    = (const float*)d_in[3];   // [H, I]
  const float* bq    = (const float*)d_in[4];   // [H]
  const float* Wk    = (const float*)d_in[5];   // [H, I]
  const float* bk    = (const float*)d_in[6];   // [H]
  const float* Wout  = (const float*)d_in[7];   // [H]

  float* attn   = (float*)d_out;                // [B, H]
  float* attn_w = (float*)d_out + (size_t)B * H;// [B, S]
  float* ws     = (float*)d_ws;

  prep_kernel<<<81, 256, 0, stream>>>(Wq, bq, Wk, bk, Wout, ws);
  main_kernel<<<dim3(B, NCH), 256, 0, stream>>>(query, key, mask, ws, attn_w);
  finish_kernel<<<dim3(B, 4), 128, 0, stream>>>(bk, ws, attn);
}